// Round 5
// baseline (383.590 us; speedup 1.0000x reference)
//
#include <hip/hip_runtime.h>
#include <cstdint>

typedef unsigned short u16;
typedef __attribute__((ext_vector_type(8))) short bf16x8;
typedef __attribute__((ext_vector_type(4))) float f32x4;

#define B_    2
#define S_    2048
#define H_    2048
#define G_    4
#define HD_   128
#define QKVW  3072   // fused QKV row width

__device__ __forceinline__ u16 f2bf(float f) {
  union { float f; unsigned u; } v; v.f = f;
  unsigned r = v.u + 0x7fffu + ((v.u >> 16) & 1u);
  return (u16)(r >> 16);
}

__device__ __forceinline__ void async16(void* lds_dst, const void* gsrc) {
  __builtin_amdgcn_global_load_lds(
      (__attribute__((address_space(1))) void*)gsrc,
      (__attribute__((address_space(3))) void*)lds_dst, 16, 0, 0);
}

// ---------------- cast fp32 -> bf16 (vectorized) ----------------
__global__ __launch_bounds__(256)
void cast_bf16_kernel(const float* __restrict__ in, u16* __restrict__ out, int n8)
{
  int i = blockIdx.x * 256 + threadIdx.x;
  if (i >= n8) return;
  const float4* p = (const float4*)in + (size_t)i * 2;
  float4 a = p[0], b = p[1];
  u16 h[8] = { f2bf(a.x), f2bf(a.y), f2bf(a.z), f2bf(a.w),
               f2bf(b.x), f2bf(b.y), f2bf(b.z), f2bf(b.w) };
  *(uint4*)(out + (size_t)i * 8) = *(const uint4*)h;
}

// ------------- transpose-cast W (K,N) fp32 -> Wt (N,K) bf16 -------------
__global__ __launch_bounds__(256)
void tcast_kernel(const float* __restrict__ W, u16* __restrict__ Wt, int Kdim, int Ndim)
{
  __shared__ float t[32][33];
  int tx = threadIdx.x & 31, ty = threadIdx.x >> 5;   // ty 0..7
  int n0 = blockIdx.x * 32, k0 = blockIdx.y * 32;
#pragma unroll
  for (int j = 0; j < 4; ++j)
    t[ty + j * 8][tx] = W[(size_t)(k0 + ty + j * 8) * Ndim + n0 + tx];
  __syncthreads();
#pragma unroll
  for (int j = 0; j < 4; ++j)
    Wt[(size_t)(n0 + ty + j * 8) * Kdim + k0 + tx] = f2bf(t[tx][ty + j * 8]);
}

// ------------- transpose V rows (stride QKVW) -> Vt (B,G,HD,S) bf16 -------------
__global__ __launch_bounds__(256)
void vtrans_kernel(const u16* __restrict__ Vb, u16* __restrict__ Vt)
{
  __shared__ u16 t[32][33];
  int tx = threadIdx.x & 31, ty = threadIdx.x >> 5;
  int s0 = blockIdx.x * 32, c0 = blockIdx.y * 32, b = blockIdx.z;
#pragma unroll
  for (int j = 0; j < 4; ++j)
    t[ty + j * 8][tx] = Vb[((size_t)(b * S_) + s0 + ty + j * 8) * QKVW + c0 + tx];
  __syncthreads();
#pragma unroll
  for (int j = 0; j < 4; ++j) {
    int c = c0 + ty + j * 8;
    int g = c >> 7, d = c & 127;
    Vt[(((size_t)(b * G_ + g)) * HD_ + d) * S_ + s0 + tx] = t[tx][ty + j * 8];
  }
}

// ---------------- GEMM: C(M,N) = A(M,K) @ Bt(N,K)^T + bias ----------------
// MODE: 1 = f32 out (bias), 3 = fused QKV bf16 out (bias select, Q-scale cols<2048)
template <int MODE>
__global__ __launch_bounds__(256)
void gemm_bt(const u16* __restrict__ A, const u16* __restrict__ Bt,
             const float* __restrict__ biasQ, const float* __restrict__ biasK,
             const float* __restrict__ biasV, void* __restrict__ Cout,
             int Ndim, int Kdim)
{
  __shared__ u16 As[128 * 64];
  __shared__ u16 Bs[128 * 64];
  const int lane = threadIdx.x & 63;
  const int wv   = threadIdx.x >> 6;

  // XCD-aware bijective chunked swizzle (nwg % 8 == 0 for all our grids)
  const int nwg  = gridDim.x * gridDim.y;
  const int wgid = blockIdx.x + gridDim.x * blockIdx.y;
  const int cpx  = nwg >> 3;
  const int swz  = (wgid & 7) * cpx + (wgid >> 3);
  const int row0 = (swz % gridDim.x) * 128;
  const int col0 = (swz / gridDim.x) * 128;

  const int wm = (wv >> 1) * 64;
  const int wn = (wv & 1) * 64;
  const int l15 = lane & 15, l4 = lane >> 4;

  f32x4 acc[4][4] = {};

  for (int kt = 0; kt < Kdim; kt += 64) {
    __syncthreads();
#pragma unroll
    for (int i = 0; i < 4; ++i) {        // stage A tile 128x64 (16KB)
      int c = (wv * 4 + i) * 64 + lane;
      int r = c >> 3, ci = c & 7;
      async16((char*)As + (wv * 4 + i) * 1024,
              A + (size_t)(row0 + r) * Kdim + kt + ci * 8);
    }
#pragma unroll
    for (int i = 0; i < 4; ++i) {        // stage B tile 128x64
      int c = (wv * 4 + i) * 64 + lane;
      int r = c >> 3, ci = c & 7;
      async16((char*)Bs + (wv * 4 + i) * 1024,
              Bt + (size_t)(col0 + r) * Kdim + kt + ci * 8);
    }
    __syncthreads();
#pragma unroll
    for (int ks = 0; ks < 2; ++ks) {
      bf16x8 af[4], bfr[4];
#pragma unroll
      for (int mt = 0; mt < 4; ++mt)
        af[mt] = *(const bf16x8*)&As[(wm + mt * 16 + l15) * 64 + ks * 32 + l4 * 8];
#pragma unroll
      for (int nt = 0; nt < 4; ++nt)
        bfr[nt] = *(const bf16x8*)&Bs[(wn + nt * 16 + l15) * 64 + ks * 32 + l4 * 8];
#pragma unroll
      for (int mt = 0; mt < 4; ++mt)
#pragma unroll
        for (int nt = 0; nt < 4; ++nt)
          acc[mt][nt] = __builtin_amdgcn_mfma_f32_16x16x32_bf16(af[mt], bfr[nt], acc[mt][nt], 0, 0, 0);
    }
  }

#pragma unroll
  for (int mt = 0; mt < 4; ++mt)
#pragma unroll
    for (int nt = 0; nt < 4; ++nt)
#pragma unroll
      for (int r = 0; r < 4; ++r) {
        int rr = row0 + wm + mt * 16 + l4 * 4 + r;    // C/D: row=(lane>>4)*4+reg
        int cc = col0 + wn + nt * 16 + l15;           //      col=lane&15
        float bias;
        if (MODE == 3)
          bias = cc < 2048 ? biasQ[cc] : (cc < 2560 ? biasK[cc - 2048] : biasV[cc - 2560]);
        else
          bias = biasQ[cc];
        float v = acc[mt][nt][r] + bias;
        if (MODE == 3 && cc < 2048) v *= 0.08838834764831845f;   // Q pre-scale
        if (MODE == 1) ((float*)Cout)[(size_t)rr * Ndim + cc] = v;
        else           ((u16*)Cout)[(size_t)rr * Ndim + cc] = f2bf(v);
      }
}

// ---------------- Flash attention (GQA) ----------------
// 4 waves x 32 q-rows = 128 q-rows/block (256 thr), KVB=64, double-buffered
// K/V, 2-phase pipeline, T2 swizzles (unchanged layouts; rg index doubles
// per-wave rows -> halves LDS reads per FLOP), T5 setprio, T13 defer-max.
// LDS = 32K(K) + 32K(V) + 16K(P) = 80KB -> 2 blocks/CU.
__global__ __launch_bounds__(256)
void attn_kernel(const u16* __restrict__ Qb, const u16* __restrict__ Kb,
                 const u16* __restrict__ Vt, u16* __restrict__ Ob)
{
  __shared__ u16 Ks[2][64 * 128];   // K tiles (64 kv x 128 d), swizzled; Q staged here first
  __shared__ u16 Vs[2][128 * 64];   // V^T tiles (128 d x 64 kv), swizzled
  __shared__ u16 Ps[128 * 64];      // P tile, 16B-granule XOR-swizzled by row&7
  const int tid  = threadIdx.x;
  const int lane = tid & 63, wv = tid >> 6;   // wv 0..3
  const int l15 = lane & 15, l4 = lane >> 4;
  const int qt = blockIdx.x, head = blockIdx.y, b = blockIdx.z;
  const int g = head >> 2;
  const int s0 = qt * 128;

  // --- stage Q (128 rows x 128 cols) into Ks area, source col pre-swizzled ---
  u16* Qlds = (u16*)Ks;
#pragma unroll
  for (int i = 0; i < 8; ++i) {
    int u = i * 256 + tid;
    int r = u >> 4;
    int ci = (u & 15) ^ (r & 7);
    async16((char*)Qlds + (i * 256 + wv * 64) * 16,
            Qb + ((size_t)(b * S_ + s0 + r)) * QKVW + head * HD_ + ci * 8);
  }
  __syncthreads();
  bf16x8 qf[2][4];
#pragma unroll
  for (int rg = 0; rg < 2; ++rg) {
    int row = wv * 32 + rg * 16 + l15;
#pragma unroll
    for (int ks = 0; ks < 4; ++ks)
      qf[rg][ks] = *(const bf16x8*)&Qlds[row * 128 + ((ks * 32 + l4 * 8) ^ ((l15 & 7) << 3))];
  }
  __syncthreads();   // all waves done reading Q before K staging overwrites it

  float m_r[2][4], l_r[2][4];
#pragma unroll
  for (int rg = 0; rg < 2; ++rg)
#pragma unroll
    for (int r = 0; r < 4; ++r) { m_r[rg][r] = -1e30f; l_r[rg][r] = 0.f; }
  f32x4 aco[2][8] = {};

#define STAGE_K(buf, kt_)                                                      \
  _Pragma("unroll")                                                            \
  for (int i = 0; i < 4; ++i) {                                                \
    int u = i * 256 + tid;                                                     \
    int r = u >> 4;                                                            \
    int ci = (u & 15) ^ (r & 7);                                               \
    async16((char*)Ks[buf] + (i * 256 + wv * 64) * 16,                         \
            Kb + ((size_t)(b * S_ + (kt_) * 64 + r)) * QKVW + g * HD_ + ci * 8); \
  }
#define STAGE_V(buf, kt_)                                                      \
  _Pragma("unroll")                                                            \
  for (int i = 0; i < 4; ++i) {                                                \
    int u = i * 256 + tid;                                                     \
    int r = u >> 3;                                                            \
    int ci = (u & 7) ^ (r & 7);                                                \
    async16((char*)Vs[buf] + (i * 256 + wv * 64) * 16,                         \
            Vt + (((size_t)(b * G_ + g)) * HD_ + r) * S_ + (kt_) * 64 + ci * 8); \
  }

  STAGE_K(0, 0);
  STAGE_V(0, 0);
  __syncthreads();   // tile 0 resident

  int cur = 0;
  for (int kt = 0; kt < S_ / 64; ++kt) {
    if (kt + 1 < S_ / 64) {    // issue next tile early; lands during compute
      STAGE_K(cur ^ 1, kt + 1);
      STAGE_V(cur ^ 1, kt + 1);
    }

    // QK^T: wave's 32 q-rows x 64 kv-cols; each kf feeds both row-groups
    f32x4 sc[2][4] = {};
    __builtin_amdgcn_s_setprio(1);
#pragma unroll
    for (int ct = 0; ct < 4; ++ct)
#pragma unroll
      for (int ks = 0; ks < 4; ++ks) {
        bf16x8 kf = *(const bf16x8*)&Ks[cur][(ct * 16 + l15) * 128 + ((ks * 32 + l4 * 8) ^ ((l15 & 7) << 3))];
        sc[0][ct] = __builtin_amdgcn_mfma_f32_16x16x32_bf16(qf[0][ks], kf, sc[0][ct], 0, 0, 0);
        sc[1][ct] = __builtin_amdgcn_mfma_f32_16x16x32_bf16(qf[1][ks], kf, sc[1][ct], 0, 0, 0);
      }
    __builtin_amdgcn_s_setprio(0);

    float mx[2][4];
#pragma unroll
    for (int rg = 0; rg < 2; ++rg) {
#pragma unroll
      for (int r = 0; r < 4; ++r) mx[rg][r] = -1e30f;
#pragma unroll
      for (int ct = 0; ct < 4; ++ct)
#pragma unroll
        for (int r = 0; r < 4; ++r)
          mx[rg][r] = fmaxf(mx[rg][r], sc[rg][ct][r]);
#pragma unroll
      for (int r = 0; r < 4; ++r) {
        mx[rg][r] = fmaxf(mx[rg][r], __shfl_xor(mx[rg][r], 1));
        mx[rg][r] = fmaxf(mx[rg][r], __shfl_xor(mx[rg][r], 2));
        mx[rg][r] = fmaxf(mx[rg][r], __shfl_xor(mx[rg][r], 4));
        mx[rg][r] = fmaxf(mx[rg][r], __shfl_xor(mx[rg][r], 8));
      }
    }

    // T13 defer-max: skip rescale unless some row grew past THR=8
    bool resc = false;
#pragma unroll
    for (int rg = 0; rg < 2; ++rg)
#pragma unroll
      for (int r = 0; r < 4; ++r) resc |= (mx[rg][r] - m_r[rg][r] > 8.0f);
    if (__ballot(resc)) {
#pragma unroll
      for (int rg = 0; rg < 2; ++rg)
#pragma unroll
        for (int r = 0; r < 4; ++r) {
          float mn = fmaxf(m_r[rg][r], mx[rg][r]);
          float al = __expf(m_r[rg][r] - mn);
          m_r[rg][r] = mn;
          l_r[rg][r] *= al;
#pragma unroll
          for (int dt = 0; dt < 8; ++dt)
            aco[rg][dt][r] *= al;
        }
    }

#pragma unroll
    for (int rg = 0; rg < 2; ++rg) {
      float sm[4] = { 0.f, 0.f, 0.f, 0.f };
#pragma unroll
      for (int ct = 0; ct < 4; ++ct)
#pragma unroll
        for (int r = 0; r < 4; ++r) {
          float p = __expf(sc[rg][ct][r] - m_r[rg][r]);
          sm[r] += p;
          int row = wv * 32 + rg * 16 + l4 * 4 + r;
          int col = ct * 16 + l15;
          Ps[row * 64 + (((col >> 3) ^ (row & 7)) << 3) + (col & 7)] = f2bf(p);
        }
#pragma unroll
      for (int r = 0; r < 4; ++r) {
        sm[r] += __shfl_xor(sm[r], 1);
        sm[r] += __shfl_xor(sm[r], 2);
        sm[r] += __shfl_xor(sm[r], 4);
        sm[r] += __shfl_xor(sm[r], 8);
        l_r[rg][r] += sm[r];
      }
    }

    // PV: O(32 x 128) += P(32 x 64) @ V(64 x 128); each vf feeds both row-groups
    __builtin_amdgcn_s_setprio(1);
#pragma unroll
    for (int k2 = 0; k2 < 2; ++k2) {
      bf16x8 pa[2];
#pragma unroll
      for (int rg = 0; rg < 2; ++rg) {
        int prow = wv * 32 + rg * 16 + l15;
        pa[rg] = *(const bf16x8*)&Ps[prow * 64 + ((((k2 * 4 + l4) ^ (l15 & 7))) << 3)];
      }
#pragma unroll
      for (int dt = 0; dt < 8; ++dt) {
        bf16x8 vf = *(const bf16x8*)&Vs[cur][(dt * 16 + l15) * 64 + ((k2 * 32 + l4 * 8) ^ ((l15 & 7) << 3))];
        aco[0][dt] = __builtin_amdgcn_mfma_f32_16x16x32_bf16(pa[0], vf, aco[0][dt], 0, 0, 0);
        aco[1][dt] = __builtin_amdgcn_mfma_f32_16x16x32_bf16(pa[1], vf, aco[1][dt], 0, 0, 0);
      }
    }
    __builtin_amdgcn_s_setprio(0);

    __syncthreads();   // drains next-tile loads (overlapped with this compute) + buf handoff
    cur ^= 1;
  }
#undef STAGE_K
#undef STAGE_V

#pragma unroll
  for (int rg = 0; rg < 2; ++rg) {
#pragma unroll
    for (int r = 0; r < 4; ++r) l_r[rg][r] = 1.0f / l_r[rg][r];
#pragma unroll
    for (int dt = 0; dt < 8; ++dt)
#pragma unroll
      for (int r = 0; r < 4; ++r) {
        int srow = s0 + wv * 32 + rg * 16 + l4 * 4 + r;
        int col = head * HD_ + dt * 16 + l15;
        Ob[((size_t)(b * S_ + srow)) * H_ + col] = f2bf(aco[rg][dt][r] * l_r[rg][r]);
      }
  }
}

extern "C" void kernel_launch(void* const* d_in, const int* in_sizes, int n_in,
                              void* d_out, int out_size, void* d_ws, size_t ws_size,
                              hipStream_t stream)
{
  const float* X    = (const float*)d_in[0];
  const float* Wq   = (const float*)d_in[2];
  const float* bq   = (const float*)d_in[3];
  const float* Wk   = (const float*)d_in[4];
  const float* bk   = (const float*)d_in[5];
  const float* Wv   = (const float*)d_in[6];
  const float* bv   = (const float*)d_in[7];
  const float* Wo   = (const float*)d_in[8];
  const float* bo   = (const float*)d_in[9];
  float* out = (float*)d_out;

  char* ws = (char*)d_ws;
  u16* Xb    = (u16*)(ws + 0);                       // 16 MiB  X bf16 (4096 x 2048)
  u16* QKV   = (u16*)(ws + (16u << 20));             // 24 MiB  QKV bf16 (4096 x 3072)
  u16* Vt    = (u16*)(ws + (40u << 20));             //  4 MiB  V^T bf16 (B,G,HD,S)
  u16* Ab    = (u16*)(ws + (44u << 20));             // 16 MiB  attn out bf16 (4096 x 2048)
  u16* Wqkvt = (u16*)(ws + (60u << 20));             // 12 MiB  (3072 x 2048)
  u16* Wot   = (u16*)(ws + (72u << 20));             //  8 MiB  -> total 80 MiB

  const u16* Qb = QKV;            // cols 0..2047   (stride QKVW)
  const u16* Kb = QKV + 2048;     // cols 2048..2559
  const u16* Vb = QKV + 2560;     // cols 2560..3071

  // casts / transposes
  cast_bf16_kernel<<<dim3(4096), 256, 0, stream>>>(X, Xb, (B_ * S_ * H_) / 8);
  tcast_kernel<<<dim3(64, 64), 256, 0, stream>>>(Wq, Wqkvt, 2048, 2048);
  tcast_kernel<<<dim3(16, 64), 256, 0, stream>>>(Wk, Wqkvt + (size_t)2048 * 2048, 2048, 512);
  tcast_kernel<<<dim3(16, 64), 256, 0, stream>>>(Wv, Wqkvt + (size_t)2560 * 2048, 2048, 512);
  tcast_kernel<<<dim3(64, 64), 256, 0, stream>>>(Wo, Wot, 2048, 2048);

  // fused QKV projection (bias select + Q pre-scale in epilogue)
  gemm_bt<3><<<dim3(32, 24), 256, 0, stream>>>(Xb, Wqkvt, bq, bk, bv, QKV, QKVW, 2048);

  vtrans_kernel<<<dim3(64, 16, 2), 256, 0, stream>>>(Vb, Vt);

  attn_kernel<<<dim3(16, 16, 2), 256, 0, stream>>>(Qb, Kb, Vt, Ab);

  // output projection (fp32 out + bias)
  gemm_bt<1><<<dim3(32, 16), 256, 0, stream>>>(Ab, Wot, bo, nullptr, nullptr, out, 2048, 2048);
}

// Round 6
// 308.911 us; speedup vs baseline: 1.2418x; 1.2418x over previous
//
#include <hip/hip_runtime.h>
#include <cstdint>

typedef unsigned short u16;
typedef __attribute__((ext_vector_type(8))) short bf16x8;
typedef __attribute__((ext_vector_type(4))) float f32x4;

#define B_    2
#define S_    2048
#define H_    2048
#define G_    4
#define HD_   128
#define QKVW  3072   // fused QKV row width

__device__ __forceinline__ u16 f2bf(float f) {
  union { float f; unsigned u; } v; v.f = f;
  unsigned r = v.u + 0x7fffu + ((v.u >> 16) & 1u);
  return (u16)(r >> 16);
}

__device__ __forceinline__ void async16(void* lds_dst, const void* gsrc) {
  __builtin_amdgcn_global_load_lds(
      (__attribute__((address_space(1))) void*)gsrc,
      (__attribute__((address_space(3))) void*)lds_dst, 16, 0, 0);
}

// ---------------- cast fp32 -> bf16 (vectorized) ----------------
__global__ __launch_bounds__(256)
void cast_bf16_kernel(const float* __restrict__ in, u16* __restrict__ out, int n8)
{
  int i = blockIdx.x * 256 + threadIdx.x;
  if (i >= n8) return;
  const float4* p = (const float4*)in + (size_t)i * 2;
  float4 a = p[0], b = p[1];
  u16 h[8] = { f2bf(a.x), f2bf(a.y), f2bf(a.z), f2bf(a.w),
               f2bf(b.x), f2bf(b.y), f2bf(b.z), f2bf(b.w) };
  *(uint4*)(out + (size_t)i * 8) = *(const uint4*)h;
}

// ------------- transpose-cast W (K,N) fp32 -> Wt (N,K) bf16 -------------
__global__ __launch_bounds__(256)
void tcast_kernel(const float* __restrict__ W, u16* __restrict__ Wt, int Kdim, int Ndim)
{
  __shared__ float t[32][33];
  int tx = threadIdx.x & 31, ty = threadIdx.x >> 5;   // ty 0..7
  int n0 = blockIdx.x * 32, k0 = blockIdx.y * 32;
#pragma unroll
  for (int j = 0; j < 4; ++j)
    t[ty + j * 8][tx] = W[(size_t)(k0 + ty + j * 8) * Ndim + n0 + tx];
  __syncthreads();
#pragma unroll
  for (int j = 0; j < 4; ++j)
    Wt[(size_t)(n0 + ty + j * 8) * Kdim + k0 + tx] = f2bf(t[tx][ty + j * 8]);
}

// ------------- transpose V rows (stride QKVW) -> Vt (B,G,HD,S) bf16 -------------
__global__ __launch_bounds__(256)
void vtrans_kernel(const u16* __restrict__ Vb, u16* __restrict__ Vt)
{
  __shared__ u16 t[32][33];
  int tx = threadIdx.x & 31, ty = threadIdx.x >> 5;
  int s0 = blockIdx.x * 32, c0 = blockIdx.y * 32, b = blockIdx.z;
#pragma unroll
  for (int j = 0; j < 4; ++j)
    t[ty + j * 8][tx] = Vb[((size_t)(b * S_) + s0 + ty + j * 8) * QKVW + c0 + tx];
  __syncthreads();
#pragma unroll
  for (int j = 0; j < 4; ++j) {
    int c = c0 + ty + j * 8;
    int g = c >> 7, d = c & 127;
    Vt[(((size_t)(b * G_ + g)) * HD_ + d) * S_ + s0 + tx] = t[tx][ty + j * 8];
  }
}

// ---------------- GEMM: C(M,N) = A(M,K) @ Bt(N,K)^T + bias ----------------
// MODE: 1 = f32 out (bias), 3 = fused QKV bf16 out (bias select, Q-scale cols<2048)
template <int MODE>
__global__ __launch_bounds__(256)
void gemm_bt(const u16* __restrict__ A, const u16* __restrict__ Bt,
             const float* __restrict__ biasQ, const float* __restrict__ biasK,
             const float* __restrict__ biasV, void* __restrict__ Cout,
             int Ndim, int Kdim)
{
  __shared__ u16 As[128 * 64];
  __shared__ u16 Bs[128 * 64];
  const int lane = threadIdx.x & 63;
  const int wv   = threadIdx.x >> 6;

  // XCD-aware bijective chunked swizzle (nwg % 8 == 0 for all our grids)
  const int nwg  = gridDim.x * gridDim.y;
  const int wgid = blockIdx.x + gridDim.x * blockIdx.y;
  const int cpx  = nwg >> 3;
  const int swz  = (wgid & 7) * cpx + (wgid >> 3);
  const int row0 = (swz % gridDim.x) * 128;
  const int col0 = (swz / gridDim.x) * 128;

  const int wm = (wv >> 1) * 64;
  const int wn = (wv & 1) * 64;
  const int l15 = lane & 15, l4 = lane >> 4;

  f32x4 acc[4][4] = {};

  for (int kt = 0; kt < Kdim; kt += 64) {
    __syncthreads();
#pragma unroll
    for (int i = 0; i < 4; ++i) {        // stage A tile 128x64 (16KB)
      int c = (wv * 4 + i) * 64 + lane;
      int r = c >> 3, ci = c & 7;
      async16((char*)As + (wv * 4 + i) * 1024,
              A + (size_t)(row0 + r) * Kdim + kt + ci * 8);
    }
#pragma unroll
    for (int i = 0; i < 4; ++i) {        // stage B tile 128x64
      int c = (wv * 4 + i) * 64 + lane;
      int r = c >> 3, ci = c & 7;
      async16((char*)Bs + (wv * 4 + i) * 1024,
              Bt + (size_t)(col0 + r) * Kdim + kt + ci * 8);
    }
    __syncthreads();
#pragma unroll
    for (int ks = 0; ks < 2; ++ks) {
      bf16x8 af[4], bfr[4];
#pragma unroll
      for (int mt = 0; mt < 4; ++mt)
        af[mt] = *(const bf16x8*)&As[(wm + mt * 16 + l15) * 64 + ks * 32 + l4 * 8];
#pragma unroll
      for (int nt = 0; nt < 4; ++nt)
        bfr[nt] = *(const bf16x8*)&Bs[(wn + nt * 16 + l15) * 64 + ks * 32 + l4 * 8];
#pragma unroll
      for (int mt = 0; mt < 4; ++mt)
#pragma unroll
        for (int nt = 0; nt < 4; ++nt)
          acc[mt][nt] = __builtin_amdgcn_mfma_f32_16x16x32_bf16(af[mt], bfr[nt], acc[mt][nt], 0, 0, 0);
    }
  }

#pragma unroll
  for (int mt = 0; mt < 4; ++mt)
#pragma unroll
    for (int nt = 0; nt < 4; ++nt)
#pragma unroll
      for (int r = 0; r < 4; ++r) {
        int rr = row0 + wm + mt * 16 + l4 * 4 + r;    // C/D: row=(lane>>4)*4+reg
        int cc = col0 + wn + nt * 16 + l15;           //      col=lane&15
        float bias;
        if (MODE == 3)
          bias = cc < 2048 ? biasQ[cc] : (cc < 2560 ? biasK[cc - 2048] : biasV[cc - 2560]);
        else
          bias = biasQ[cc];
        float v = acc[mt][nt][r] + bias;
        if (MODE == 3 && cc < 2048) v *= 0.08838834764831845f;   // Q pre-scale
        if (MODE == 1) ((float*)Cout)[(size_t)rr * Ndim + cc] = v;
        else           ((u16*)Cout)[(size_t)rr * Ndim + cc] = f2bf(v);
      }
}

// ---------------- Flash attention (GQA) ----------------
// Round-4 structure (the proven one): 8 waves x 16 q-rows = 128 q-rows/block
// (512 thr, VGPR ~64), KVB=64, double-buffered K/V, 2-phase pipeline,
// T2 swizzles, T5 setprio, T13 defer-max. LDS = 80KB -> 2 blocks/CU.
// Q/K read from the fused QKV buffer (row stride QKVW).
__global__ __launch_bounds__(512)
void attn_kernel(const u16* __restrict__ Qb, const u16* __restrict__ Kb,
                 const u16* __restrict__ Vt, u16* __restrict__ Ob)
{
  __shared__ u16 Ks[2][64 * 128];   // K tiles (64 kv x 128 d), swizzled
  __shared__ u16 Vs[2][128 * 64];   // V^T tiles (128 d x 64 kv), swizzled; Q staged here first
  __shared__ u16 Ps[128 * 64];      // P tile, 16B-granule XOR-swizzled by row&7
  const int tid  = threadIdx.x;
  const int lane = tid & 63, wv = tid >> 6;   // wv 0..7
  const int l15 = lane & 15, l4 = lane >> 4;
  const int qt = blockIdx.x, head = blockIdx.y, b = blockIdx.z;
  const int g = head >> 2;
  const int s0 = qt * 128;

  // --- stage Q (128 rows x 256B) into Vs area, source col pre-swizzled ---
  u16* Qlds = (u16*)Vs;
#pragma unroll
  for (int i = 0; i < 4; ++i) {
    int u = i * 512 + tid;
    int r = u >> 4;
    int ci = (u & 15) ^ (r & 7);
    async16((char*)Qlds + (i * 512 + wv * 64) * 16,
            Qb + ((size_t)(b * S_ + s0 + r)) * QKVW + head * HD_ + ci * 8);
  }
  __syncthreads();
  bf16x8 qf[4];
  {
    int row = wv * 16 + l15;
#pragma unroll
    for (int ks = 0; ks < 4; ++ks)
      qf[ks] = *(const bf16x8*)&Qlds[row * 128 + ((ks * 32 + l4 * 8) ^ ((l15 & 7) << 3))];
  }
  __syncthreads();   // all waves done reading Q before V staging overwrites it

  float m_r[4] = { -1e30f, -1e30f, -1e30f, -1e30f };
  float l_r[4] = { 0.f, 0.f, 0.f, 0.f };
  f32x4 aco[8] = {};

#define STAGE_K(buf, kt_)                                                      \
  _Pragma("unroll")                                                            \
  for (int i = 0; i < 2; ++i) {                                                \
    int u = i * 512 + tid;                                                     \
    int r = u >> 4;                                                            \
    int ci = (u & 15) ^ (r & 7);                                               \
    async16((char*)Ks[buf] + (i * 512 + wv * 64) * 16,                         \
            Kb + ((size_t)(b * S_ + (kt_) * 64 + r)) * QKVW + g * HD_ + ci * 8); \
  }
#define STAGE_V(buf, kt_)                                                      \
  _Pragma("unroll")                                                            \
  for (int i = 0; i < 2; ++i) {                                                \
    int u = i * 512 + tid;                                                     \
    int r = u >> 3;                                                            \
    int ci = (u & 7) ^ (r & 7);                                                \
    async16((char*)Vs[buf] + (i * 512 + wv * 64) * 16,                         \
            Vt + (((size_t)(b * G_ + g)) * HD_ + r) * S_ + (kt_) * 64 + ci * 8); \
  }

  STAGE_K(0, 0);
  STAGE_V(0, 0);
  __syncthreads();   // tile 0 resident

  int cur = 0;
  for (int kt = 0; kt < S_ / 64; ++kt) {
    if (kt + 1 < S_ / 64) {    // issue next tile early; lands during compute
      STAGE_K(cur ^ 1, kt + 1);
      STAGE_V(cur ^ 1, kt + 1);
    }

    // QK^T: wave's 16 q-rows x 64 kv-cols (Q pre-scaled)
    f32x4 sc[4] = {};
    __builtin_amdgcn_s_setprio(1);
#pragma unroll
    for (int ct = 0; ct < 4; ++ct)
#pragma unroll
      for (int ks = 0; ks < 4; ++ks) {
        bf16x8 kf = *(const bf16x8*)&Ks[cur][(ct * 16 + l15) * 128 + ((ks * 32 + l4 * 8) ^ ((l15 & 7) << 3))];
        sc[ct] = __builtin_amdgcn_mfma_f32_16x16x32_bf16(qf[ks], kf, sc[ct], 0, 0, 0);
      }
    __builtin_amdgcn_s_setprio(0);

    float mx[4] = { -1e30f, -1e30f, -1e30f, -1e30f };
#pragma unroll
    for (int ct = 0; ct < 4; ++ct)
#pragma unroll
      for (int r = 0; r < 4; ++r)
        mx[r] = fmaxf(mx[r], sc[ct][r]);
#pragma unroll
    for (int r = 0; r < 4; ++r) {
      mx[r] = fmaxf(mx[r], __shfl_xor(mx[r], 1));
      mx[r] = fmaxf(mx[r], __shfl_xor(mx[r], 2));
      mx[r] = fmaxf(mx[r], __shfl_xor(mx[r], 4));
      mx[r] = fmaxf(mx[r], __shfl_xor(mx[r], 8));
    }

    // T13 defer-max: skip rescale unless some row grew past THR=8
    bool resc = false;
#pragma unroll
    for (int r = 0; r < 4; ++r) resc |= (mx[r] - m_r[r] > 8.0f);
    if (__ballot(resc)) {
#pragma unroll
      for (int r = 0; r < 4; ++r) {
        float mn = fmaxf(m_r[r], mx[r]);
        float al = __expf(m_r[r] - mn);
        m_r[r] = mn;
        l_r[r] *= al;
#pragma unroll
        for (int dt = 0; dt < 8; ++dt)
          aco[dt][r] *= al;
      }
    }

    float sm[4] = { 0.f, 0.f, 0.f, 0.f };
#pragma unroll
    for (int ct = 0; ct < 4; ++ct)
#pragma unroll
      for (int r = 0; r < 4; ++r) {
        float p = __expf(sc[ct][r] - m_r[r]);
        sm[r] += p;
        // P[row][col], row = wv*16+l4*4+r, col = ct*16+l15; granule-swizzled
        int row = wv * 16 + l4 * 4 + r;
        int col = ct * 16 + l15;
        Ps[row * 64 + (((col >> 3) ^ (row & 7)) << 3) + (col & 7)] = f2bf(p);
      }
#pragma unroll
    for (int r = 0; r < 4; ++r) {
      sm[r] += __shfl_xor(sm[r], 1);
      sm[r] += __shfl_xor(sm[r], 2);
      sm[r] += __shfl_xor(sm[r], 4);
      sm[r] += __shfl_xor(sm[r], 8);
      l_r[r] += sm[r];
    }

    // PV: O(16 x 128) += P(16 x 64) @ V(64 x 128)
    __builtin_amdgcn_s_setprio(1);
#pragma unroll
    for (int k2 = 0; k2 < 2; ++k2) {
      int prow = wv * 16 + l15;
      bf16x8 pa = *(const bf16x8*)&Ps[prow * 64 + ((((k2 * 4 + l4) ^ (l15 & 7))) << 3)];
#pragma unroll
      for (int dt = 0; dt < 8; ++dt) {
        bf16x8 vf = *(const bf16x8*)&Vs[cur][(dt * 16 + l15) * 64 + ((k2 * 32 + l4 * 8) ^ ((l15 & 7) << 3))];
        aco[dt] = __builtin_amdgcn_mfma_f32_16x16x32_bf16(pa, vf, aco[dt], 0, 0, 0);
      }
    }
    __builtin_amdgcn_s_setprio(0);

    __syncthreads();   // drains next-tile loads (overlapped with this compute) + buf handoff
    cur ^= 1;
  }
#undef STAGE_K
#undef STAGE_V

#pragma unroll
  for (int r = 0; r < 4; ++r) l_r[r] = 1.0f / l_r[r];
#pragma unroll
  for (int dt = 0; dt < 8; ++dt)
#pragma unroll
    for (int r = 0; r < 4; ++r) {
      int srow = s0 + wv * 16 + l4 * 4 + r;
      int col = head * HD_ + dt * 16 + l15;
      Ob[((size_t)(b * S_ + srow)) * H_ + col] = f2bf(aco[dt][r] * l_r[r]);
    }
}

extern "C" void kernel_launch(void* const* d_in, const int* in_sizes, int n_in,
                              void* d_out, int out_size, void* d_ws, size_t ws_size,
                              hipStream_t stream)
{
  const float* X    = (const float*)d_in[0];
  const float* Wq   = (const float*)d_in[2];
  const float* bq   = (const float*)d_in[3];
  const float* Wk   = (const float*)d_in[4];
  const float* bk   = (const float*)d_in[5];
  const float* Wv   = (const float*)d_in[6];
  const float* bv   = (const float*)d_in[7];
  const float* Wo   = (const float*)d_in[8];
  const float* bo   = (const float*)d_in[9];
  float* out = (float*)d_out;

  char* ws = (char*)d_ws;
  u16* Xb    = (u16*)(ws + 0);                       // 16 MiB  X bf16 (4096 x 2048)
  u16* QKV   = (u16*)(ws + (16u << 20));             // 24 MiB  QKV bf16 (4096 x 3072)
  u16* Vt    = (u16*)(ws + (40u << 20));             //  4 MiB  V^T bf16 (B,G,HD,S)
  u16* Ab    = (u16*)(ws + (44u << 20));             // 16 MiB  attn out bf16 (4096 x 2048)
  u16* Wqkvt = (u16*)(ws + (60u << 20));             // 12 MiB  (3072 x 2048)
  u16* Wot   = (u16*)(ws + (72u << 20));             //  8 MiB  -> total 80 MiB

  const u16* Qb = QKV;            // cols 0..2047   (stride QKVW)
  const u16* Kb = QKV + 2048;     // cols 2048..2559
  const u16* Vb = QKV + 2560;     // cols 2560..3071

  // casts / transposes
  cast_bf16_kernel<<<dim3(4096), 256, 0, stream>>>(X, Xb, (B_ * S_ * H_) / 8);
  tcast_kernel<<<dim3(64, 64), 256, 0, stream>>>(Wq, Wqkvt, 2048, 2048);
  tcast_kernel<<<dim3(16, 64), 256, 0, stream>>>(Wk, Wqkvt + (size_t)2048 * 2048, 2048, 512);
  tcast_kernel<<<dim3(16, 64), 256, 0, stream>>>(Wv, Wqkvt + (size_t)2560 * 2048, 2048, 512);
  tcast_kernel<<<dim3(64, 64), 256, 0, stream>>>(Wo, Wot, 2048, 2048);

  // fused QKV projection (bias select + Q pre-scale in epilogue)
  gemm_bt<3><<<dim3(32, 24), 256, 0, stream>>>(Xb, Wqkvt, bq, bk, bv, QKV, QKVW, 2048);

  vtrans_kernel<<<dim3(64, 16, 2), 256, 0, stream>>>(Vb, Vt);

  attn_kernel<<<dim3(16, 16, 2), 512, 0, stream>>>(Qb, Kb, Vt, Ab);

  // output projection (fp32 out + bias)
  gemm_bt<1><<<dim3(32, 16), 256, 0, stream>>>(Ab, Wot, bo, nullptr, nullptr, out, 2048, 2048);
}